// Round 1
// baseline (61855.463 us; speedup 1.0000x reference)
//
#include <hip/hip_runtime.h>
#include <math.h>

#define NB 128        // batch
#define KPH 3         // phrases
#define MAXPER 48
#define MAXTOK 144
#define LATENT 128
#define HD 512
#define NMEM 8
#define NH 8
#define VOC 8000
#define DHD 64
#define CT 145        // cache slots = MAX_TOK+1
#define ATTN_SCALE 0.125f

// ---------------------------------------------------------------------------
// zero-fill
__global__ void k_zero(float* __restrict__ p, int n) {
  int i = blockIdx.x * blockDim.x + threadIdx.x;
  if (i < n) p[i] = 0.0f;
}

// weighted_z = z_weights[:,None] * z_seq   ([B*K, LATENT])
__global__ void k_wz(const float* __restrict__ z_seq, const float* __restrict__ zw,
                     float* __restrict__ out) {
  int i = blockIdx.x * blockDim.x + threadIdx.x;
  if (i < NB * KPH * LATENT) out[i] = zw[i >> 7] * z_seq[i];
}

// ---------------------------------------------------------------------------
// generic tiled fp32 GEMM: out[b, ooff + c] = epi( A[b,:K] @ W[:K, c] (+R[b,c]) )
// grid (N/64, M/32), block 256. Residual stride fixed at 512 (only N=512 uses R).
__global__ __launch_bounds__(256) void k_gemm(
    const float* __restrict__ A, int lda,
    const float* __restrict__ W, int ldw, int K,
    const float* __restrict__ R, float* __restrict__ out,
    int ostride, int ooff, int dogelu)
{
  __shared__ float As[32][36];
  __shared__ float Ws[32][64];
  const int t = threadIdx.x;
  const int c0 = blockIdx.x * 64, b0 = blockIdx.y * 32;
  const int c = t & 63, g = t >> 6;
  float acc[8] = {0,0,0,0,0,0,0,0};
  const int ra = t >> 3, ka = (t & 7) << 2;
  for (int k0 = 0; k0 < K; k0 += 32) {
    const float4 a4 = *reinterpret_cast<const float4*>(A + (size_t)(b0 + ra) * lda + k0 + ka);
    As[ra][ka] = a4.x; As[ra][ka+1] = a4.y; As[ra][ka+2] = a4.z; As[ra][ka+3] = a4.w;
    #pragma unroll
    for (int e = 0; e < 8; e++) {
      int li = t + e * 256;
      Ws[li >> 6][li & 63] = W[(size_t)(k0 + (li >> 6)) * ldw + c0 + (li & 63)];
    }
    __syncthreads();
    #pragma unroll
    for (int kk = 0; kk < 32; kk++) {
      float wv = Ws[kk][c];
      #pragma unroll
      for (int i = 0; i < 8; i++) acc[i] += As[g*8+i][kk] * wv;
    }
    __syncthreads();
  }
  #pragma unroll
  for (int i = 0; i < 8; i++) {
    int b = b0 + g * 8 + i;
    float v = acc[i];
    if (R) v += R[(size_t)b * 512 + c0 + c];
    if (dogelu) {
      float x3 = v * v * v;
      v = 0.5f * v * (1.0f + tanhf(0.7978845608028654f * (v + 0.044715f * x3)));
    }
    out[(size_t)b * ostride + ooff + c0 + c] = v;
  }
}

// ---------------------------------------------------------------------------
// logits tile + per-(b,tile) argmax partial. grid (125, 4), block 256.
__global__ __launch_bounds__(256) void k_logits(
    const float* __restrict__ A, const float* __restrict__ W,
    float* __restrict__ pv, int* __restrict__ pi)
{
  __shared__ float As[32][36];
  __shared__ float Ws[32][64];
  __shared__ float rv[32][65];
  const int t = threadIdx.x;
  const int c0 = blockIdx.x * 64, b0 = blockIdx.y * 32;
  const int c = t & 63, g = t >> 6;
  float acc[8] = {0,0,0,0,0,0,0,0};
  const int ra = t >> 3, ka = (t & 7) << 2;
  for (int k0 = 0; k0 < 512; k0 += 32) {
    const float4 a4 = *reinterpret_cast<const float4*>(A + (size_t)(b0 + ra) * 512 + k0 + ka);
    As[ra][ka] = a4.x; As[ra][ka+1] = a4.y; As[ra][ka+2] = a4.z; As[ra][ka+3] = a4.w;
    #pragma unroll
    for (int e = 0; e < 8; e++) {
      int li = t + e * 256;
      Ws[li >> 6][li & 63] = W[(size_t)(k0 + (li >> 6)) * VOC + c0 + (li & 63)];
    }
    __syncthreads();
    #pragma unroll
    for (int kk = 0; kk < 32; kk++) {
      float wv = Ws[kk][c];
      #pragma unroll
      for (int i = 0; i < 8; i++) acc[i] += As[g*8+i][kk] * wv;
    }
    __syncthreads();
  }
  #pragma unroll
  for (int i = 0; i < 8; i++) rv[g*8+i][c] = acc[i];
  __syncthreads();
  if (t < 32) {
    float best = rv[t][0]; int bi = 0;
    for (int cc = 1; cc < 64; cc++) {       // serial -> first-max tie-break
      float v = rv[t][cc];
      if (v > best) { best = v; bi = cc; }
    }
    pv[(size_t)(b0 + t) * 128 + blockIdx.x] = best;
    pi[(size_t)(b0 + t) * 128 + blockIdx.x] = c0 + bi;
  }
}

// ---------------------------------------------------------------------------
// init: active flags, state, gate, x_in = emb[BOS]. grid NB, block 128.
__global__ void k_init(const float* __restrict__ zw, const float* __restrict__ temb,
                       float* __restrict__ xin, float* __restrict__ gf, int* __restrict__ iph,
                       int* __restrict__ cur, int* __restrict__ tip, int* __restrict__ pos,
                       int* __restrict__ done, int* __restrict__ act)
{
  int b = blockIdx.x;
  if (threadIdx.x == 0) {
    int a0 = zw[b*3+0] > 0.01f;
    act[b*3+0] = a0;
    act[b*3+1] = zw[b*3+1] > 0.01f;
    act[b*3+2] = zw[b*3+2] > 0.01f;
    cur[b] = 0; tip[b] = 0; pos[b] = 0; done[b] = !a0;
    gf[b] = a0 ? 1.0f : 0.0f; iph[b] = 0;
  }
  for (int c = threadIdx.x; c < HD; c += blockDim.x)
    xin[(size_t)b * HD + c] = temb[1 * HD + c];    // BOS = 1
}

// ---------------------------------------------------------------------------
// per-b: finish argmax, run state machine, emit outputs, gather next emb.
// grid NB, block 128.
__global__ void k_state(const float* __restrict__ pv, const int* __restrict__ pi,
                        const float* __restrict__ temb, const float* __restrict__ x,
                        float* __restrict__ xin,
                        int* __restrict__ cur, int* __restrict__ tip, int* __restrict__ pos,
                        int* __restrict__ done, const int* __restrict__ act,
                        float* __restrict__ gf, int* __restrict__ iph,
                        float* __restrict__ tok_out, float* __restrict__ gen_out,
                        float* __restrict__ bnd_out, float* __restrict__ hid_out)
{
  int b = blockIdx.x, t = threadIdx.x;
  __shared__ float sv[128];
  __shared__ int   si[128];
  __shared__ int   s_nxt;
  float v = -INFINITY; int idx = 0x7fffffff;
  if (t < 125) { v = pv[(size_t)b * 128 + t]; idx = pi[(size_t)b * 128 + t]; }
  sv[t] = v; si[t] = idx;
  __syncthreads();
  for (int s = 64; s > 0; s >>= 1) {
    if (t < s) {
      float v2 = sv[t + s]; int i2 = si[t + s];
      if (v2 > sv[t] || (v2 == sv[t] && i2 < si[t])) { sv[t] = v2; si[t] = i2; }
    }
    __syncthreads();
  }
  if (t == 0) {
    int nxt = si[0]; s_nxt = nxt;
    int dn = done[b]; int live = !dn;
    int p = pos[b], tp = tip[b], cp = cur[b];
    if (p < MAXTOK) {
      tok_out[(size_t)b * MAXTOK + p] = live ? (float)nxt : 0.0f;
      gen_out[(size_t)b * MAXTOK + p] = live ? 1.0f : 0.0f;
    }
    p += live; tp += live;
    int eos = (nxt == 2) && (tp >= 1);
    int sw = (eos || (tp >= MAXPER)) && live;
    cp += sw;
    if (sw) tp = 0;
    int cpc = cp < 2 ? cp : 2;
    int svw = sw && (cp < KPH);
    if (svw) bnd_out[(size_t)b * KPH + cpc] = (float)p;
    dn = dn || (cp >= KPH) || (sw && !act[b*3 + cpc]);
    cur[b] = cp; tip[b] = tp; pos[b] = p; done[b] = dn;
    gf[b] = (act[b*3 + cpc] && !dn) ? 1.0f : 0.0f;
    iph[b] = cpc;
  }
  __syncthreads();
  int nxt = s_nxt;
  for (int c = t; c < HD; c += 128) {
    xin[(size_t)b * HD + c]     = temb[(size_t)nxt * HD + c];
    hid_out[(size_t)b * HD + c] = x[(size_t)b * HD + c];
  }
}

// ---------------------------------------------------------------------------
// self-attention: one wave per (b,h). grid (NB, NH), block 64.
__global__ void k_attn(const float* __restrict__ q, const float* __restrict__ kc,
                       const float* __restrict__ vc, float* __restrict__ sa, int T)
{
  int b = blockIdx.x, h = blockIdx.y, lane = threadIdx.x;
  __shared__ float ql[64];
  __shared__ float sc[160];
  ql[lane] = q[(size_t)b * HD + h * DHD + lane];
  __syncthreads();
  float lmax = -INFINITY;
  for (int s0 = lane; s0 < T; s0 += 64) {
    const float* kp = kc + (size_t)b * CT * HD + (size_t)s0 * HD + h * DHD;
    float d = 0.0f;
    #pragma unroll
    for (int e = 0; e < DHD; e++) d += ql[e] * kp[e];
    d *= ATTN_SCALE;
    sc[s0] = d;
    if (d > lmax) lmax = d;
  }
  #pragma unroll
  for (int off = 32; off > 0; off >>= 1) { float o = __shfl_xor(lmax, off); lmax = fmaxf(lmax, o); }
  __syncthreads();
  float lsum = 0.0f;
  for (int s0 = lane; s0 < T; s0 += 64) {
    float e = expf(sc[s0] - lmax);
    sc[s0] = e; lsum += e;
  }
  #pragma unroll
  for (int off = 32; off > 0; off >>= 1) lsum += __shfl_xor(lsum, off);
  __syncthreads();
  float inv = 1.0f / lsum;
  float acc = 0.0f;
  const float* vb = vc + (size_t)b * CT * HD + h * DHD + lane;
  for (int s0 = 0; s0 < T; s0++) acc += sc[s0] * vb[(size_t)s0 * HD];
  sa[(size_t)b * HD + h * DHD + lane] = acc * inv;
}

// ---------------------------------------------------------------------------
// cross-attention over NMEM memory slots: one wave per (b,h). grid (NB, NH), block 64.
__global__ void k_cross(const float* __restrict__ cq, const float* __restrict__ MCK,
                        const float* __restrict__ MCV, const float* __restrict__ gf,
                        const int* __restrict__ iph, float* __restrict__ ca)
{
  int b = blockIdx.x, h = blockIdx.y, lane = threadIdx.x;
  __shared__ float ql[64];
  __shared__ float s[NMEM];
  float gate = gf[b];
  int ip = iph[b];
  ql[lane] = cq[(size_t)b * HD + h * DHD + lane];
  __syncthreads();
  const float* kb = MCK + ((size_t)(b * KPH + ip) * NMEM) * HD;
  if (lane < NMEM) {
    const float* kp = kb + (size_t)lane * HD + h * DHD;
    float d = 0.0f;
    #pragma unroll
    for (int e = 0; e < DHD; e++) d += ql[e] * kp[e];
    s[lane] = d * ATTN_SCALE * gate;
  }
  __syncthreads();
  float mx = s[0];
  #pragma unroll
  for (int m = 1; m < NMEM; m++) mx = fmaxf(mx, s[m]);
  float e[NMEM]; float sum = 0.0f;
  #pragma unroll
  for (int m = 0; m < NMEM; m++) { e[m] = expf(s[m] - mx); sum += e[m]; }
  const float* vb = MCV + ((size_t)(b * KPH + ip) * NMEM) * HD + h * DHD + lane;
  float a = 0.0f;
  #pragma unroll
  for (int m = 0; m < NMEM; m++) a += e[m] * vb[(size_t)m * HD];
  ca[(size_t)b * HD + h * DHD + lane] = gate * a / sum;
}

// ---------------------------------------------------------------------------
extern "C" void kernel_launch(void* const* d_in, const int* in_sizes, int n_in,
                              void* d_out, int out_size, void* d_ws, size_t ws_size,
                              hipStream_t stream)
{
  const float* z_seq = (const float*)d_in[0];
  const float* z_w   = (const float*)d_in[1];
  const float* W_l2d = (const float*)d_in[2];
  const float* temb  = (const float*)d_in[3];
  const float* Wq  = (const float*)d_in[4];
  const float* Wk  = (const float*)d_in[5];
  const float* Wv  = (const float*)d_in[6];
  const float* Wo  = (const float*)d_in[7];
  const float* Wcq = (const float*)d_in[8];
  const float* Wck = (const float*)d_in[9];
  const float* Wcv = (const float*)d_in[10];
  const float* Wco = (const float*)d_in[11];
  const float* W1  = (const float*)d_in[12];
  const float* W2  = (const float*)d_in[13];
  const float* Wout= (const float*)d_in[14];

  float* fw = (float*)d_ws;
  size_t o = 0;
  auto alloc = [&](size_t n) { size_t r = o; o += (n + 255) & ~(size_t)255; return r; };
  float* MCK = fw + alloc((size_t)NB*KPH*NMEM*HD);   // 1.57M
  float* MCV = fw + alloc((size_t)NB*KPH*NMEM*HD);
  float* MEM = fw + alloc((size_t)NB*KPH*NMEM*HD);   // memories
  float* KC  = fw + alloc((size_t)NB*CT*HD);         // 9.5M
  float* VC  = fw + alloc((size_t)NB*CT*HD);
  float* X   = fw + alloc((size_t)NB*HD);
  float* XIN = fw + alloc((size_t)NB*HD);
  float* X2  = fw + alloc((size_t)NB*HD);
  float* X3  = fw + alloc((size_t)NB*HD);
  float* SAb = fw + alloc((size_t)NB*HD);
  float* CAb = fw + alloc((size_t)NB*HD);
  float* Qb  = fw + alloc((size_t)NB*HD);
  float* CQb = fw + alloc((size_t)NB*HD);
  float* H1  = fw + alloc((size_t)NB*4*HD);
  float* WZ  = fw + alloc((size_t)NB*KPH*LATENT);
  float* PV  = fw + alloc((size_t)NB*128);
  float* GF  = fw + alloc((size_t)NB);
  int* ib = (int*)(fw + alloc(0));
  size_t io = 0;
  auto ialloc = [&](size_t n) { size_t r = io; io += (n + 255) & ~(size_t)255; return r; };
  int* PI  = ib + ialloc((size_t)NB*128);
  int* CUR = ib + ialloc(NB);
  int* TIP = ib + ialloc(NB);
  int* POS = ib + ialloc(NB);
  int* DONE= ib + ialloc(NB);
  int* IPH = ib + ialloc(NB);
  int* ACT = ib + ialloc(NB*KPH);

  float* out_f = (float*)d_out;
  float* TOK  = out_f;
  float* GEN  = out_f + NB*MAXTOK;
  float* BND  = out_f + 2*NB*MAXTOK;
  float* HIDb = out_f + 2*NB*MAXTOK + NB*KPH;

  // ---- once-per-call setup ----
  int nz = 2*NB*MAXTOK + NB*KPH;
  k_zero<<<(nz + 255)/256, 256, 0, stream>>>(out_f, nz);
  k_wz<<<(NB*KPH*LATENT + 255)/256, 256, 0, stream>>>(z_seq, z_w, WZ);
  // memories[B*K, 4096] = WZ[B*K,128] @ W_l2d[128,4096]
  k_gemm<<<dim3(64,12),256,0,stream>>>(WZ,128, W_l2d,4096,128, nullptr, MEM, 4096,0,0);
  // MCK/MCV[B*K*NMEM, 512] = memories[3072,512] @ Wck/Wcv
  k_gemm<<<dim3(8,96),256,0,stream>>>(MEM,512, Wck,512,512, nullptr, MCK,512,0,0);
  k_gemm<<<dim3(8,96),256,0,stream>>>(MEM,512, Wcv,512,512, nullptr, MCV,512,0,0);
  k_init<<<NB,128,0,stream>>>(z_w, temb, XIN, GF, IPH, CUR, TIP, POS, DONE, ACT);

  auto chain = [&](int slot, int T) {
    k_gemm<<<dim3(8,4),256,0,stream>>>(XIN,512, Wq,512,512, nullptr, Qb,512,0,0);
    k_gemm<<<dim3(8,4),256,0,stream>>>(XIN,512, Wk,512,512, nullptr, KC, CT*HD, slot*HD, 0);
    k_gemm<<<dim3(8,4),256,0,stream>>>(XIN,512, Wv,512,512, nullptr, VC, CT*HD, slot*HD, 0);
    k_attn<<<dim3(NB,NH),64,0,stream>>>(Qb, KC, VC, SAb, T);
    k_gemm<<<dim3(8,4),256,0,stream>>>(SAb,512, Wo,512,512, XIN, X2,512,0,0);   // x2 = xin + sa@Wo
    k_gemm<<<dim3(8,4),256,0,stream>>>(X2,512, Wcq,512,512, nullptr, CQb,512,0,0);
    k_cross<<<dim3(NB,NH),64,0,stream>>>(CQb, MCK, MCV, GF, IPH, CAb);
    k_gemm<<<dim3(8,4),256,0,stream>>>(CAb,512, Wco,512,512, X2, X3,512,0,0);   // x3 = x2 + ca@Wco
    k_gemm<<<dim3(32,4),256,0,stream>>>(X3,512, W1,2048,512, nullptr, H1,2048,0,1); // gelu
    k_gemm<<<dim3(8,4),256,0,stream>>>(H1,2048, W2,512,2048, X3, X,512,0,0);    // x = x3 + h1@W2
  };

  chain(0, 1);                       // initial attn_step on BOS, cache slot 0
  for (int t = 0; t < MAXTOK; t++) {
    k_logits<<<dim3(125,4),256,0,stream>>>(X, Wout, PV, PI);
    k_state<<<NB,128,0,stream>>>(PV, PI, temb, X, XIN, CUR, TIP, POS, DONE, ACT,
                                 GF, IPH, TOK, GEN, BND, HIDb + (size_t)t*NB*HD);
    chain(t + 1, t + 2);
  }
}